// Round 5
// baseline (2936.502 us; speedup 1.0000x reference)
//
#include <hip/hip_runtime.h>

typedef _Float16 f16;
typedef __attribute__((ext_vector_type(4))) _Float16 f16x4;
typedef __attribute__((ext_vector_type(8))) _Float16 f16x8;
typedef __attribute__((ext_vector_type(4))) float f32x4;

__device__ __forceinline__ float tanh_fast(float x) {
  // tanh(x) = 1 - 2/(exp(2x)+1); hw exp + hw rcp (endpoints exact)
  float e = __expf(2.0f * x);
  return 1.0f - 2.0f * __builtin_amdgcn_rcpf(e + 1.0f);
}

// raw LDS-only workgroup sync: no vmcnt drain (keeps global prefetches alive)
__device__ __forceinline__ void wg_sync_lds() {
  asm volatile("s_waitcnt lgkmcnt(0)" ::: "memory");
  __builtin_amdgcn_sched_barrier(0);
  __builtin_amdgcn_s_barrier();
  __builtin_amdgcn_sched_barrier(0);
}

#if defined(__has_builtin)
#if __has_builtin(__builtin_amdgcn_global_load_lds)
#define USE_GLL 1
#endif
#endif
#ifndef USE_GLL
#define USE_GLL 0
#endif

__device__ __forceinline__ void gll16(const void* g, void* l) {
#if USE_GLL
  __builtin_amdgcn_global_load_lds(
      (const __attribute__((address_space(1))) unsigned int*)g,
      (__attribute__((address_space(3))) unsigned int*)l, 16, 0, 0);
#endif
}

// ---------------- fp32 -> fp16 convert (grid-stride, float4) ----------------
__global__ void k_cvt_f16(const float* __restrict__ in, f16* __restrict__ out, int n4) {
  int i = blockIdx.x * blockDim.x + threadIdx.x;
  int stride = gridDim.x * blockDim.x;
  for (; i < n4; i += stride) {
    float4 v = reinterpret_cast<const float4*>(in)[i];
    f16x4 o;
    o[0] = (f16)v.x; o[1] = (f16)v.y; o[2] = (f16)v.z; o[3] = (f16)v.w;
    *reinterpret_cast<f16x4*>(out + (size_t)i * 4) = o;
  }
}

// ------------- 512x512 transpose + convert: out[n][k] = f16(in[k][n]) -------
__global__ __launch_bounds__(256) void k_transpose_cvt(const float* __restrict__ in,
                                                       f16* __restrict__ out) {
  __shared__ float tile[32][33];
  int bx = blockIdx.x & 15, by = blockIdx.x >> 4;
  int tx = threadIdx.x & 31, ty = threadIdx.x >> 5;  // ty in 0..7
#pragma unroll
  for (int i = 0; i < 4; ++i)
    tile[ty + i * 8][tx] = in[(size_t)(by * 32 + ty + i * 8) * 512 + bx * 32 + tx];
  __syncthreads();
#pragma unroll
  for (int i = 0; i < 4; ++i)
    out[(size_t)(bx * 32 + ty + i * 8) * 512 + by * 32 + tx] = (f16)tile[tx][ty + i * 8];
}

// --------- W_hh frag-pack: Wf[cb][kt][q][c][e] = f16(W_hh[kt*32+q*8+e][cb*16+c])
__global__ __launch_bounds__(256) void k_packW(const float* __restrict__ Whh,
                                               f16* __restrict__ Wf) {
  int id = blockIdx.x * 256 + threadIdx.x;  // 0..32767, one 16B block each
  int c = id & 15, q = (id >> 4) & 3, kt = (id >> 6) & 15, cb = id >> 10;
  f16x8 blk;
#pragma unroll
  for (int e = 0; e < 8; ++e)
    blk[e] = (f16)Whh[(size_t)(kt * 32 + q * 8 + e) * 512 + cb * 16 + c];
  reinterpret_cast<f16x8*>(Wf)[id] = blk;
}

// ---------------- fp16 MFMA GEMM: C[M][N] = A[M][K] * Bt[N][K]^T + bias -----
// OUT: 0 = f32 linear, 2 = f16 packed-xw (scan-ready layout)
#define BM 128
#define BN 128
#define BK 32

template <int OUT>
__global__ __launch_bounds__(256, 2) void k_gemm(const f16* __restrict__ A,
                                                 const f16* __restrict__ Bt,
                                                 const float* __restrict__ bias,
                                                 void* __restrict__ Cout,
                                                 int M, int N, int K) {
  __shared__ __align__(16) f16 As[2][BM][BK];
  __shared__ __align__(16) f16 Bs[2][BN][BK];

  const int tid = threadIdx.x;
  const int w = tid >> 6;  // wave 0..3
  const int l = tid & 63;  // lane
  const int nbn = N / BN;
  const int bm0 = (int)(blockIdx.x / nbn) * BM;
  const int bn0 = (int)(blockIdx.x % nbn) * BN;
  const int wm = w >> 1, wn = w & 1;

  auto stage = [&](int buf, int kt) {
#pragma unroll
    for (int c = 0; c < 2; ++c) {
      const int row = c * 64 + w * 16 + (l >> 2);
      const int ke = kt + (l & 3) * 8;
#if USE_GLL
      gll16(A + (size_t)(bm0 + row) * K + ke, &As[buf][c * 64 + w * 16][0]);
      gll16(Bt + (size_t)(bn0 + row) * K + ke, &Bs[buf][c * 64 + w * 16][0]);
#else
      *(f16x8*)&As[buf][row][(l & 3) * 8] = *(const f16x8*)(A + (size_t)(bm0 + row) * K + ke);
      *(f16x8*)&Bs[buf][row][(l & 3) * 8] = *(const f16x8*)(Bt + (size_t)(bn0 + row) * K + ke);
#endif
    }
  };

  f32x4 acc[4][4] = {};
  const int nkt = K / BK;
  stage(0, 0);
  int cur = 0;
  for (int kt = 0; kt < nkt; ++kt) {
    __syncthreads();
    if (kt + 1 < nkt) stage(cur ^ 1, (kt + 1) * BK);
    f16x8 af[4], bfr[4];
#pragma unroll
    for (int m = 0; m < 4; ++m)
      af[m] = *(const f16x8*)&As[cur][wm * 64 + m * 16 + (l & 15)][(l >> 4) * 8];
#pragma unroll
    for (int n = 0; n < 4; ++n)
      bfr[n] = *(const f16x8*)&Bs[cur][wn * 64 + n * 16 + (l & 15)][(l >> 4) * 8];
#pragma unroll
    for (int m = 0; m < 4; ++m)
#pragma unroll
      for (int n = 0; n < 4; ++n)
        acc[m][n] = __builtin_amdgcn_mfma_f32_16x16x32_f16(af[m], bfr[n], acc[m][n], 0, 0, 0);
    cur ^= 1;
  }

  // Epilogue. C/D layout: col = lane&15, row = (lane>>4)*4 + j  [HW-verified]
  const int r0 = bm0 + wm * 64, c0 = bn0 + wn * 64;
#pragma unroll
  for (int n = 0; n < 4; ++n) {
    const int cc = c0 + n * 16 + (l & 15);
    const float bv = bias[cc];
#pragma unroll
    for (int m = 0; m < 4; ++m) {
      const int rr = r0 + m * 16 + ((l >> 4) << 2);
      if (OUT == 2) {
        // packed xw: element (Mrow=rr+j, cc), Mrow=(b<<10)|t
        const int b = rr >> 10, trow = rr & 1023;
        const int set = b >> 4, qq = (b >> 2) & 3, jj = b & 3;
        const int cb = cc >> 4, ww = cb & 7, ii = cb >> 3, c2 = cc & 15;
        size_t idx =
            ((((((size_t)set * 256 + (trow >> 2)) * 8 + ww) * 4 + qq) * 4 + jj) * 16 + c2) * 16 +
            ii * 4;
        f16x4 pk;
#pragma unroll
        for (int j = 0; j < 4; ++j) pk[j] = (f16)(acc[m][n][j] + bv);
        *(f16x4*)((f16*)Cout + idx) = pk;
      } else {
#pragma unroll
        for (int j = 0; j < 4; ++j)
          ((float*)Cout)[(size_t)(rr + j) * N + cc] = acc[m][n][j] + bv;
      }
    }
  }
}

// ---------------- RNN scan: W resident on ONE CU per 16-batch set -----------
// 4 WGs x 512 threads (8 waves). Wave w owns 4 col-blocks:
//   {w, 8+w}        register-resident (128 VGPR)
//   {16+w}          kt 0..11 LDS-resident (96 KiB), kt 12..15 registers (16 VGPR)
//   {24+w}          streamed from L2, depth-4 rotating prefetch wrapping steps
// h double-buffered in LDS, row-major [16][528] with XOR swizzle
// k' = k ^ ((m>>2)<<3): conflict-free b16 writes, <=2-way b128 reads,
// ONE LDS-only barrier per step.
#define SCAN_T 1024

__global__ __launch_bounds__(512, 2) void k_scan_reg(
    const f16* __restrict__ xwp,   // packed xw (see k_gemm OUT==2)
    const f16* __restrict__ Wf,    // frag-packed [32][16][4][16][8]
    f16* __restrict__ hs,          // [64][1024][512] linear f16 (out)
    float* __restrict__ h_last) {  // [64][512] f32 (out)
  const int tid = threadIdx.x;
  const int w = tid >> 6, l = tid & 63;
  const int q = l >> 4, c = l & 15;
  const int set = blockIdx.x;
  const int b0 = set * 16;

  __shared__ __align__(16) f16 wlds[8][12][4][16][8];  // 96 KiB: cb 16..23, kt 0..11
  __shared__ __align__(16) f16 h3[2][16][528];         // 33 KiB: h double-buffered
  char* const h3b = (char*)&h3[0][0][0];

  const f16x8* WfB = (const f16x8*)Wf;
  const int cbs[4] = {w, 8 + w, 16 + w, 24 + w};

  // register-resident W frags
  f16x8 wb0[16], wb1[16], wb2[4];
#pragma unroll
  for (int kt = 0; kt < 16; ++kt) {
    wb0[kt] = WfB[((w * 16 + kt) * 4 + q) * 16 + c];
    wb1[kt] = WfB[(((8 + w) * 16 + kt) * 4 + q) * 16 + c];
  }
#pragma unroll
  for (int s = 0; s < 4; ++s)
    wb2[s] = WfB[(((16 + w) * 16 + (12 + s)) * 4 + q) * 16 + c];

  // stage LDS-resident W (cb 16..23, kt 0..11): per-wave contiguous chunks
  {
    f16* dst0 = &wlds[0][0][0][0][0];
#pragma unroll
    for (int k2 = 0; k2 < 12; ++k2) {
      gll16(WfB + ((16 + w) * 16 + k2) * 64 + l, dst0 + (size_t)((w * 12 + k2) * 64) * 8);
#if !USE_GLL
      ((f16x8*)dst0)[(w * 12 + k2) * 64 + l] = WfB[((16 + w) * 16 + k2) * 64 + l];
#endif
    }
  }
  // zero h3 (h0 = 0; both buffers)
  {
    uint4* hz = (uint4*)h3b;
    for (int i = tid; i < 2112; i += 512) hz[i] = make_uint4(0u, 0u, 0u, 0u);
  }

  // stream pointer for cb 24+w; frag kt at sp[kt*64]
  const f16x8* sp = WfB + (size_t)(24 + w) * 1024 + q * 16 + c;

  // packed-xw lane base (elements); j stride 256, tq stride 32768
  const f16* xwbase =
      xwp + (((((size_t)set * 256 * 8 + (size_t)w) * 4 + q) * 4 + 0) * 16 + c) * 16;

  // hs bases per j (element ptr incl. lane col offset c)
  f16* hsb[4];
#pragma unroll
  for (int j = 0; j < 4; ++j)
    hsb[j] = hs + (size_t)(b0 + q * 4 + j) * SCAN_T * 512 + c;

  // h3 addressing (bytes): af read base (row c, kt walks +64); write offsets
  const int afbase = c * 1056 + 16 * (q ^ (c >> 2));
  int woff[4][4];  // [i2][j] byte offset within one h buffer
#pragma unroll
  for (int i2 = 0; i2 < 4; ++i2)
#pragma unroll
    for (int j = 0; j < 4; ++j)
      woff[i2][j] = (q * 4 + j) * 1056 + (((cbs[i2] * 16 + c) ^ (q << 3)) << 1);

  // prologue prefetch: xv for tq=0, stream slots kt=0..3
  f16x8 xv[4][2];
#pragma unroll
  for (int j = 0; j < 4; ++j) {
    xv[j][0] = __builtin_nontemporal_load((const f16x8*)(xwbase + j * 256));
    xv[j][1] = __builtin_nontemporal_load((const f16x8*)(xwbase + j * 256 + 8));
  }
  f16x8 sb[4];
#pragma unroll
  for (int kk = 0; kk < 4; ++kk) sb[kk] = sp[kk * 64];

  __syncthreads();  // full sync once: wlds/h3 staged (drains gll vmcnt too)

  for (int tq = 0; tq < 256; ++tq) {
#pragma unroll
    for (int ts = 0; ts < 4; ++ts) {
      const int t = tq * 4 + ts;
      const int rbuf = ts & 1, wbuf = rbuf ^ 1;  // compile-time per unrolled ts

      // acc init from xw (C-in slot of first MFMA)
      f32x4 acc[4];
#pragma unroll
      for (int i2 = 0; i2 < 4; ++i2)
#pragma unroll
        for (int j = 0; j < 4; ++j)
          acc[i2][j] = (float)xv[j][i2 >> 1][(i2 & 1) * 4 + ts];

#pragma unroll
      for (int kt = 0; kt < 16; ++kt) {
        f16x8 af = *(const f16x8*)(h3b + rbuf * 16896 + afbase + kt * 64);
        f16x8 wl = (kt < 12) ? *(const f16x8*)&wlds[w][kt][q][c][0] : wb2[kt - 12];
        f16x8 scur = sb[kt & 3];
        sb[kt & 3] = sp[((kt + 4) & 15) * 64];  // wraps into next step's kt 0..3
        acc[0] = __builtin_amdgcn_mfma_f32_16x16x32_f16(af, wb0[kt], acc[0], 0, 0, 0);
        acc[1] = __builtin_amdgcn_mfma_f32_16x16x32_f16(af, wb1[kt], acc[1], 0, 0, 0);
        acc[2] = __builtin_amdgcn_mfma_f32_16x16x32_f16(af, wl, acc[2], 0, 0, 0);
        acc[3] = __builtin_amdgcn_mfma_f32_16x16x32_f16(af, scur, acc[3], 0, 0, 0);
      }

      if (ts == 3) {  // prefetch next tq's xw (consumed ~a full step later)
        const int tqn = (tq < 255) ? tq + 1 : 255;
        const f16* pnx = xwbase + (size_t)tqn * 32768;
#pragma unroll
        for (int j = 0; j < 4; ++j) {
          xv[j][0] = __builtin_nontemporal_load((const f16x8*)(pnx + j * 256));
          xv[j][1] = __builtin_nontemporal_load((const f16x8*)(pnx + j * 256 + 8));
        }
      }

      // tanh + h3 write (buf^1) + hs store
#pragma unroll
      for (int i2 = 0; i2 < 4; ++i2)
#pragma unroll
        for (int j = 0; j < 4; ++j) {
          float hv = tanh_fast(acc[i2][j]);
          *(f16*)(h3b + wbuf * 16896 + woff[i2][j]) = (f16)hv;
          __builtin_nontemporal_store((f16)hv, hsb[j] + (size_t)t * 512 + cbs[i2] * 16);
          if (ts == 3 && tq == 255)
            h_last[(size_t)(b0 + q * 4 + j) * 512 + cbs[i2] * 16 + c] = hv;
        }
      wg_sync_lds();  // single barrier: write(t) -> read(t+1)
    }
  }
}

// ---------------------------------------------------------------------------
extern "C" void kernel_launch(void* const* d_in, const int* in_sizes, int n_in,
                              void* d_out, int out_size, void* d_ws, size_t ws_size,
                              hipStream_t stream) {
  const float* x    = (const float*)d_in[0];  // [64][1024][512]
  const float* W_xh = (const float*)d_in[1];  // [512][512]
  const float* b_h  = (const float*)d_in[2];  // [512]
  const float* W_hh = (const float*)d_in[3];  // [512][512]
  const float* W_o  = (const float*)d_in[4];  // [512][512]
  const float* b_o  = (const float*)d_in[5];  // [512]
  float* out = (float*)d_out;                 // logits [64][1024][512] ++ h_last [64][512]

  const size_t XWN = (size_t)64 * 1024 * 512;
  char* ws = (char*)d_ws;
  f16* xf   = (f16*)(ws);                       // 64 MiB (x f16 -> later hs)
  f16* xwp  = (f16*)(ws + XWN * 2);             // 64 MiB (packed xW f16)
  f16* WxhT = (f16*)(ws + XWN * 4);             // 512 KiB
  f16* WoT  = (f16*)(ws + XWN * 4 + 524288);    // 512 KiB
  f16* Wf   = (f16*)(ws + XWN * 4 + 1048576);   // 512 KiB (frag-packed W_hh)

  // prep: converts + transposes + frag-pack
  k_cvt_f16<<<4096, 256, 0, stream>>>(x, xf, (int)(XWN / 4));
  k_transpose_cvt<<<256, 256, 0, stream>>>(W_xh, WxhT);
  k_transpose_cvt<<<256, 256, 0, stream>>>(W_o, WoT);
  k_packW<<<128, 256, 0, stream>>>(W_hh, Wf);

  // xW = x @ W_xh + b_h, written directly in scan-packed layout
  k_gemm<2><<<2048, 256, 0, stream>>>(xf, WxhT, b_h, xwp, 65536, 512, 512);

  // sequential scan: 4 self-contained WGs, no cross-WG communication
  k_scan_reg<<<4, 512, 0, stream>>>(xwp, Wf, xf /*hs*/, out + XWN);

  // logits = hs @ W_o + b_o   (f32 out)
  k_gemm<0><<<2048, 256, 0, stream>>>(xf, WoT, b_o, out, 65536, 512, 512);
}

// Round 6
// 2178.711 us; speedup vs baseline: 1.3478x; 1.3478x over previous
//
#include <hip/hip_runtime.h>

typedef _Float16 f16;
typedef __attribute__((ext_vector_type(4))) _Float16 f16x4;
typedef __attribute__((ext_vector_type(8))) _Float16 f16x8;
typedef __attribute__((ext_vector_type(4))) float f32x4;

__device__ __forceinline__ float tanh_fast(float x) {
  float e = __expf(2.0f * x);
  return 1.0f - 2.0f * __builtin_amdgcn_rcpf(e + 1.0f);
}

// raw LDS-only workgroup sync: no vmcnt drain (keeps global prefetches alive)
__device__ __forceinline__ void wg_sync_lds() {
  asm volatile("s_waitcnt lgkmcnt(0)" ::: "memory");
  __builtin_amdgcn_sched_barrier(0);
  __builtin_amdgcn_s_barrier();
  __builtin_amdgcn_sched_barrier(0);
}

#if defined(__has_builtin)
#if __has_builtin(__builtin_amdgcn_global_load_lds)
#define USE_GLL 1
#endif
#endif
#ifndef USE_GLL
#define USE_GLL 0
#endif

__device__ __forceinline__ void gll16(const void* g, void* l) {
#if USE_GLL
  __builtin_amdgcn_global_load_lds(
      (const __attribute__((address_space(1))) unsigned int*)g,
      (__attribute__((address_space(3))) unsigned int*)l, 16, 0, 0);
#endif
}

// ---------------- fp32 -> fp16 convert (grid-stride, float4) ----------------
__global__ void k_cvt_f16(const float* __restrict__ in, f16* __restrict__ out, int n4) {
  int i = blockIdx.x * blockDim.x + threadIdx.x;
  int stride = gridDim.x * blockDim.x;
  for (; i < n4; i += stride) {
    float4 v = reinterpret_cast<const float4*>(in)[i];
    f16x4 o;
    o[0] = (f16)v.x; o[1] = (f16)v.y; o[2] = (f16)v.z; o[3] = (f16)v.w;
    *reinterpret_cast<f16x4*>(out + (size_t)i * 4) = o;
  }
}

// ------------- 512x512 transpose + convert: out[n][k] = f16(in[k][n]) -------
__global__ __launch_bounds__(256) void k_transpose_cvt(const float* __restrict__ in,
                                                       f16* __restrict__ out) {
  __shared__ float tile[32][33];
  int bx = blockIdx.x & 15, by = blockIdx.x >> 4;
  int tx = threadIdx.x & 31, ty = threadIdx.x >> 5;
#pragma unroll
  for (int i = 0; i < 4; ++i)
    tile[ty + i * 8][tx] = in[(size_t)(by * 32 + ty + i * 8) * 512 + bx * 32 + tx];
  __syncthreads();
#pragma unroll
  for (int i = 0; i < 4; ++i)
    out[(size_t)(bx * 32 + ty + i * 8) * 512 + by * 32 + tx] = (f16)tile[tx][ty + i * 8];
}

// --------- W_hh frag-pack: Wf[cb][kt][q][c][e] = f16(W_hh[kt*32+q*8+e][cb*16+c])
__global__ __launch_bounds__(256) void k_packW(const float* __restrict__ Whh,
                                               f16* __restrict__ Wf) {
  int id = blockIdx.x * 256 + threadIdx.x;
  int c = id & 15, q = (id >> 4) & 3, kt = (id >> 6) & 15, cb = id >> 10;
  f16x8 blk;
#pragma unroll
  for (int e = 0; e < 8; ++e)
    blk[e] = (f16)Whh[(size_t)(kt * 32 + q * 8 + e) * 512 + cb * 16 + c];
  reinterpret_cast<f16x8*>(Wf)[id] = blk;
}

// ---------------- fp16 MFMA GEMM: C[M][N] = A[M][K] * Bt[N][K]^T + bias -----
// OUT: 0 = f32 linear, 2 = f16 packed-xw (scan-ready layout, ts-major blocks)
#define BM 128
#define BN 128
#define BK 32

template <int OUT>
__global__ __launch_bounds__(256, 2) void k_gemm(const f16* __restrict__ A,
                                                 const f16* __restrict__ Bt,
                                                 const float* __restrict__ bias,
                                                 void* __restrict__ Cout,
                                                 int M, int N, int K) {
  __shared__ __align__(16) f16 As[2][BM][BK];
  __shared__ __align__(16) f16 Bs[2][BN][BK];

  const int tid = threadIdx.x;
  const int w = tid >> 6;
  const int l = tid & 63;
  const int nbn = N / BN;
  const int bm0 = (int)(blockIdx.x / nbn) * BM;
  const int bn0 = (int)(blockIdx.x % nbn) * BN;
  const int wm = w >> 1, wn = w & 1;

  auto stage = [&](int buf, int kt) {
#pragma unroll
    for (int c = 0; c < 2; ++c) {
      const int row = c * 64 + w * 16 + (l >> 2);
      const int ke = kt + (l & 3) * 8;
#if USE_GLL
      gll16(A + (size_t)(bm0 + row) * K + ke, &As[buf][c * 64 + w * 16][0]);
      gll16(Bt + (size_t)(bn0 + row) * K + ke, &Bs[buf][c * 64 + w * 16][0]);
#else
      *(f16x8*)&As[buf][row][(l & 3) * 8] = *(const f16x8*)(A + (size_t)(bm0 + row) * K + ke);
      *(f16x8*)&Bs[buf][row][(l & 3) * 8] = *(const f16x8*)(Bt + (size_t)(bn0 + row) * K + ke);
#endif
    }
  };

  f32x4 acc[4][4] = {};
  const int nkt = K / BK;
  stage(0, 0);
  int cur = 0;
  for (int kt = 0; kt < nkt; ++kt) {
    __syncthreads();
    if (kt + 1 < nkt) stage(cur ^ 1, (kt + 1) * BK);
    f16x8 af[4], bfr[4];
#pragma unroll
    for (int m = 0; m < 4; ++m)
      af[m] = *(const f16x8*)&As[cur][wm * 64 + m * 16 + (l & 15)][(l >> 4) * 8];
#pragma unroll
    for (int n = 0; n < 4; ++n)
      bfr[n] = *(const f16x8*)&Bs[cur][wn * 64 + n * 16 + (l & 15)][(l >> 4) * 8];
#pragma unroll
    for (int m = 0; m < 4; ++m)
#pragma unroll
      for (int n = 0; n < 4; ++n)
        acc[m][n] = __builtin_amdgcn_mfma_f32_16x16x32_f16(af[m], bfr[n], acc[m][n], 0, 0, 0);
    cur ^= 1;
  }

  // Epilogue. C/D layout: col = lane&15, row = (lane>>4)*4 + j  [HW-verified]
  const int r0 = bm0 + wm * 64, c0 = bn0 + wn * 64;
#pragma unroll
  for (int n = 0; n < 4; ++n) {
    const int cc = c0 + n * 16 + (l & 15);
    const float bv = bias[cc];
#pragma unroll
    for (int m = 0; m < 4; ++m) {
      const int rr = r0 + m * 16 + ((l >> 4) << 2);
      if (OUT == 2) {
        // packed xw element (b,t,cc): idx =
        //  (((((set*256+tq)*8+w)*4+q)*4+jj)*16+c2)*16 + ts*4 + ii;  (GEMM j == ts)
        const int b = rr >> 10, trow = rr & 1023;
        const int set = b >> 4, qq = (b >> 2) & 3, jj = b & 3;
        const int ww = (cc >> 4) & 7, ii = cc >> 7, c2 = cc & 15;
        const int tq = trow >> 2;
        f16* po = (f16*)Cout +
                  ((((((size_t)set * 256 + tq) * 8 + ww) * 4 + qq) * 4 + jj) * 16 + c2) * 16 + ii;
#pragma unroll
        for (int j = 0; j < 4; ++j) po[j * 4] = (f16)(acc[m][n][j] + bv);
      } else {
#pragma unroll
        for (int j = 0; j < 4; ++j)
          ((float*)Cout)[(size_t)(rr + j) * N + cc] = acc[m][n][j] + bv;
      }
    }
  }
}

// ---------------- RNN scan: ALL of W on-CU (regs + LDS), no L2 stream -------
// 4 WGs x 512 threads (8 waves). Wave w owns cb {w, 8+w, 16+w} in REGISTERS
// (192 VGPR) and cb {24+w} in LDS (128 KiB total). h single-buffered in LDS
// ([16][528] f16, XOR swizzle col^=(row>>2)<<3 in 8-f16 blocks), 2 raw
// LDS-only barriers/step. hs written via vectorized copy-out of h(t-1).
#define SCAN_T 1024

__global__ __launch_bounds__(512, 2) void k_scan_lds(
    const f16* __restrict__ xwp,   // packed xw (see k_gemm OUT==2)
    const f16* __restrict__ Wf,    // frag-packed [32][16][4][16][8]
    f16* __restrict__ hs,          // [64][1024][512] linear f16 (out)
    float* __restrict__ h_last) {  // [64][512] f32 (out)
  const int tid = threadIdx.x;
  const int w = tid >> 6, l = tid & 63;
  const int q = l >> 4, c = l & 15;
  const int set = blockIdx.x;
  const int b0 = set * 16;

  __shared__ __align__(16) f16 wlds[8][16][4][16][8];  // 128 KiB: cb 24..31
  __shared__ __align__(16) f16 h3[16][528];            // 16.5 KiB single buffer
  char* const h3b = (char*)&h3[0][0];
  char* const wldsb = (char*)&wlds[0][0][0][0][0];

  const f16x8* WfB = (const f16x8*)Wf;

  // register-resident W: cb w, 8+w, 16+w  (192 VGPR)
  f16x8 wb0[16], wb1[16], wb2[16];
#pragma unroll
  for (int kt = 0; kt < 16; ++kt) {
    wb0[kt] = WfB[((w * 16 + kt) * 4 + q) * 16 + c];
    wb1[kt] = WfB[(((8 + w) * 16 + kt) * 4 + q) * 16 + c];
    wb2[kt] = WfB[(((16 + w) * 16 + kt) * 4 + q) * 16 + c];
  }

  // stage cb 24..31 into wlds (16 KiB per wave, async)
#pragma unroll
  for (int k2 = 0; k2 < 16; ++k2) {
    gll16(WfB + ((24 + w) * 16 + k2) * 64 + l, wldsb + (size_t)(w * 16 + k2) * 1024);
#if !USE_GLL
    ((f16x8*)wldsb)[(w * 16 + k2) * 64 + l] = WfB[((24 + w) * 16 + k2) * 64 + l];
#endif
  }
  // zero h3 (h0 = 0)
  {
    uint4* hz = (uint4*)h3b;
    for (int i = tid; i < 1056; i += 512) hz[i] = make_uint4(0u, 0u, 0u, 0u);
  }

  // addressing
  const int cbs[4] = {w, 8 + w, 16 + w, 24 + w};
  const int afbase = c * 1056 + 16 * (q ^ (c >> 2));     // + kt*64
  const int wlbase = w * 16384 + q * 256 + c * 16;       // + kt*1024
  int woff[4];
#pragma unroll
  for (int i2 = 0; i2 < 4; ++i2)
    woff[i2] = (q * 4) * 1056 + (((cbs[i2] * 16 + c) ^ (q << 3)) << 1);  // + j*1056

  // copy-out: this thread moves 32B of h row cr (real col blocks 2cs, 2cs+1)
  const int cr = tid >> 5, cs = tid & 31;
  const int cpsrc0 = cr * 1056 + ((((cs * 2) ^ (cr >> 2))) << 4);
  const int cpsrc1 = cpsrc0 ^ 16;  // (2cs+1)^k differs from (2cs)^k only in bit0
  f16* const cpdst = hs + (size_t)(b0 + cr) * SCAN_T * 512 + cs * 16;  // + (t-1)*512

  // packed-xw lane base; per (tq,ts,j): + tq*32768 + j*256 + ts*4
  const f16* xwbase =
      xwp + (((((size_t)set * 256 * 8 + w) * 4 + q) * 4 + 0) * 16 + c) * 16;

  // prologue: xv[0] = step-0 values
  f16x4 xv[2][4];
#pragma unroll
  for (int j = 0; j < 4; ++j)
    xv[0][j] = __builtin_nontemporal_load((const f16x4*)(xwbase + j * 256));

  __syncthreads();  // staging + zero complete (drains gll vmcnt too)

  for (int tq = 0; tq < 256; ++tq) {
#pragma unroll
    for (int ts = 0; ts < 4; ++ts) {
      const int t = tq * 4 + ts;
      const int p = ts & 1;

      // copy-out reads of h_prev (= hs[t-1])
      f16x8 cp0 = *(const f16x8*)(h3b + cpsrc0);
      f16x8 cp1 = *(const f16x8*)(h3b + cpsrc1);

      // acc init from xw (C-in of the chains)
      f32x4 acc[4];
#pragma unroll
      for (int i2 = 0; i2 < 4; ++i2)
#pragma unroll
        for (int j = 0; j < 4; ++j) acc[i2][j] = (float)xv[p][j][i2];

      // prefetch xw for t+1 into the other parity (covered by this step)
      {
        const int tqn = (ts == 3) ? ((tq < 255) ? tq + 1 : 255) : tq;
        const int tsn = (ts + 1) & 3;
        const f16* pb = xwbase + (size_t)tqn * 32768 + tsn * 4;
#pragma unroll
        for (int j = 0; j < 4; ++j)
          xv[p ^ 1][j] = __builtin_nontemporal_load((const f16x4*)(pb + j * 256));
      }

      // MFMA: 4 independent chains, all W on-CU
#pragma unroll
      for (int kt = 0; kt < 16; ++kt) {
        f16x8 af = *(const f16x8*)(h3b + afbase + kt * 64);
        f16x8 wl = *(const f16x8*)(wldsb + wlbase + kt * 1024);
        acc[0] = __builtin_amdgcn_mfma_f32_16x16x32_f16(af, wb0[kt], acc[0], 0, 0, 0);
        acc[1] = __builtin_amdgcn_mfma_f32_16x16x32_f16(af, wb1[kt], acc[1], 0, 0, 0);
        acc[2] = __builtin_amdgcn_mfma_f32_16x16x32_f16(af, wb2[kt], acc[2], 0, 0, 0);
        acc[3] = __builtin_amdgcn_mfma_f32_16x16x32_f16(af, wl, acc[3], 0, 0, 0);
      }
      wg_sync_lds();  // B1: all h3 reads (af + cp) complete

      // hs copy-out store for t-1 (vector, swizzle-block-relocated)
      if (t > 0) {
        f16* d = cpdst + (size_t)(t - 1) * 512;
        __builtin_nontemporal_store(cp0, (f16x8*)d);
        __builtin_nontemporal_store(cp1, (f16x8*)(d + 8));
      }

      // tanh + h3 overwrite (h_new)
#pragma unroll
      for (int i2 = 0; i2 < 4; ++i2)
#pragma unroll
        for (int j = 0; j < 4; ++j) {
          float hv = tanh_fast(acc[i2][j]);
          *(f16*)(h3b + woff[i2] + j * 1056) = (f16)hv;
        }
      wg_sync_lds();  // B2: h_new visible
    }
  }

  // epilogue: hs[1023] copy-out + h_last (f32)
  {
    f16x8 cp0 = *(const f16x8*)(h3b + cpsrc0);
    f16x8 cp1 = *(const f16x8*)(h3b + cpsrc1);
    f16* d = cpdst + (size_t)(SCAN_T - 1) * 512;
    __builtin_nontemporal_store(cp0, (f16x8*)d);
    __builtin_nontemporal_store(cp1, (f16x8*)(d + 8));
    float* hl = h_last + (size_t)(b0 + cr) * 512 + cs * 16;
    float4 o0, o1, o2, o3;
    o0.x = (float)cp0[0]; o0.y = (float)cp0[1]; o0.z = (float)cp0[2]; o0.w = (float)cp0[3];
    o1.x = (float)cp0[4]; o1.y = (float)cp0[5]; o1.z = (float)cp0[6]; o1.w = (float)cp0[7];
    o2.x = (float)cp1[0]; o2.y = (float)cp1[1]; o2.z = (float)cp1[2]; o2.w = (float)cp1[3];
    o3.x = (float)cp1[4]; o3.y = (float)cp1[5]; o3.z = (float)cp1[6]; o3.w = (float)cp1[7];
    *(float4*)(hl + 0) = o0;
    *(float4*)(hl + 4) = o1;
    *(float4*)(hl + 8) = o2;
    *(float4*)(hl + 12) = o3;
  }
}

// ---------------------------------------------------------------------------
extern "C" void kernel_launch(void* const* d_in, const int* in_sizes, int n_in,
                              void* d_out, int out_size, void* d_ws, size_t ws_size,
                              hipStream_t stream) {
  const float* x    = (const float*)d_in[0];
  const float* W_xh = (const float*)d_in[1];
  const float* b_h  = (const float*)d_in[2];
  const float* W_hh = (const float*)d_in[3];
  const float* W_o  = (const float*)d_in[4];
  const float* b_o  = (const float*)d_in[5];
  float* out = (float*)d_out;  // logits [64][1024][512] ++ h_last [64][512]

  const size_t XWN = (size_t)64 * 1024 * 512;
  char* ws = (char*)d_ws;
  f16* xf   = (f16*)(ws);                       // 64 MiB (x f16 -> later hs)
  f16* xwp  = (f16*)(ws + XWN * 2);             // 64 MiB (packed xW f16)
  f16* WxhT = (f16*)(ws + XWN * 4);             // 512 KiB
  f16* WoT  = (f16*)(ws + XWN * 4 + 524288);    // 512 KiB
  f16* Wf   = (f16*)(ws + XWN * 4 + 1048576);   // 512 KiB (frag-packed W_hh)

  k_cvt_f16<<<4096, 256, 0, stream>>>(x, xf, (int)(XWN / 4));
  k_transpose_cvt<<<256, 256, 0, stream>>>(W_xh, WxhT);
  k_transpose_cvt<<<256, 256, 0, stream>>>(W_o, WoT);
  k_packW<<<128, 256, 0, stream>>>(W_hh, Wf);

  // xW = x @ W_xh + b_h, written in scan-packed (ts-major) layout
  k_gemm<2><<<2048, 256, 0, stream>>>(xf, WxhT, b_h, xwp, 65536, 512, 512);

  // sequential scan: 4 self-contained WGs, all W on-CU
  k_scan_lds<<<4, 512, 0, stream>>>(xwp, Wf, xf /*hs*/, out + XWN);

  // logits = hs @ W_o + b_o   (f32 out)
  k_gemm<0><<<2048, 256, 0, stream>>>(xf, WoT, b_o, out, 65536, 512, 512);
}